// Round 11
// baseline (1999.822 us; speedup 1.0000x reference)
//
#include <hip/hip_runtime.h>

#define C 128
#define NCH 4

typedef __attribute__((ext_vector_type(4))) float float4v;
typedef _Float16 half8v __attribute__((ext_vector_type(8)));
typedef _Float16 half4v __attribute__((ext_vector_type(4)));

// LDS swizzle (fp16, row stride 128 elems, 16 chunks of 8)
__device__ __forceinline__ _Float16* swzh(_Float16* base, int row, int chunk) {
  return base + row * 128 + ((chunk ^ (row & 15)) << 3);
}

// ---------------- degree count per (src-chunk, dst) ---------------------
__global__ void k_degree(const int* __restrict__ row, const int* __restrict__ col,
                         int* __restrict__ cntc, int E, int N, int CH) {
  int e = blockIdx.x * blockDim.x + threadIdx.x;
  if (e >= E) return;
  int c = row[e] / CH;
  atomicAdd(&cntc[c * N + col[e]], 1);
}

// ---------------- dis[i] = rsqrt(total deg + 1) -------------------------
__global__ void k_dis(const int* __restrict__ cntc, float* __restrict__ dis, int N) {
  int i = blockIdx.x * 256 + threadIdx.x;
  if (i >= N) return;
  int d = 0;
#pragma unroll
  for (int c = 0; c < NCH; ++c) d += cntc[c * N + i];
  dis[i] = rsqrtf((float)(d + 1));
}

// ---------------- single-block scan over M entries ----------------------
__global__ void k_scan(const int* __restrict__ cnt, int* __restrict__ indptr,
                       int* __restrict__ cursor, int M) {
  __shared__ int sb[1024];
  int t = threadIdx.x;
  int chunk = (M + 1023) >> 10;
  int lo = t * chunk, hi = min(lo + chunk, M);
  int sum = 0;
  for (int i = lo; i < hi; ++i) sum += cnt[i];
  sb[t] = sum;
  __syncthreads();
  for (int off = 1; off < 1024; off <<= 1) {
    int v = (t >= off) ? sb[t - off] : 0;
    __syncthreads();
    sb[t] += v;
    __syncthreads();
  }
  int run = sb[t] - sum;
  for (int i = lo; i < hi; ++i) {
    indptr[i] = run; cursor[i] = run;
    run += cnt[i];
  }
  if (lo < M && hi == M) indptr[M] = run;
}

// ---------------- CSR fill ((src-chunk, dst)-sorted) --------------------
__global__ void k_csrfill(const int* __restrict__ row, const int* __restrict__ col,
                          const float* __restrict__ dis, int* __restrict__ cursor,
                          int2* __restrict__ emeta, int2* __restrict__ epair,
                          int* __restrict__ inv, int E, int N, int CH) {
  int e = blockIdx.x * blockDim.x + threadIdx.x;
  if (e >= E) return;
  int r = row[e], c = col[e];
  int ch = r / CH;
  int pos = atomicAdd(&cursor[ch * N + c], 1);
  float nrm = dis[r] * dis[c];
  emeta[pos] = make_int2(r, __float_as_int(nrm));
  epair[pos] = make_int2(r, c);
  inv[e] = pos;
}

// ---------------- x fp32 -> fp16 ----------------------------------------
__global__ void k_cvt(const float* __restrict__ x, _Float16* __restrict__ xh, int n4) {
  int i = blockIdx.x * 256 + threadIdx.x;
  if (i >= n4) return;
  float4 v = ((const float4*)x)[i];
  half4v o = {(_Float16)v.x, (_Float16)v.y, (_Float16)v.z, (_Float16)v.w};
  *(half4v*)(xh + i * 4) = o;
}

// ---------------- W1 -> fp16 fragment-major table (fc1) ------------------
__global__ void k_prepwf(const float* __restrict__ W1, _Float16* __restrict__ Wf) {
  int idx = blockIdx.x * 256 + threadIdx.x;  // 16384
  int e = idx & 7, lane = (idx >> 3) & 63, j = (idx >> 9) & 7, kk = idx >> 12;
  int n = j * 16 + (lane & 15);
  int k = (kk * 4 + (lane >> 4)) * 8 + e;
  Wf[idx] = (_Float16)W1[k * C + n];
}

// ------- conv/fc0 W -> fragment-major fp16 hi + scaled-lo (10 mats) ------
__global__ void k_prepw2(const float* __restrict__ convs_W,
                         const float* __restrict__ fc0_W,
                         _Float16* __restrict__ Wfh, _Float16* __restrict__ Wfl) {
  int g = blockIdx.x * 256 + threadIdx.x;  // [0, 10*16384)
  int mat = g >> 14, idx = g & 16383;
  int e = idx & 7, lane = (idx >> 3) & 63, j = (idx >> 9) & 7, kk = idx >> 12;
  int n = j * 16 + (lane & 15);
  int k = (kk * 4 + (lane >> 4)) * 8 + e;
  const float* src = (mat < 8) ? convs_W + ((size_t)mat << 14)
                               : fc0_W + ((size_t)(mat - 8) << 14);
  float v = src[k * C + n];
  _Float16 h = (_Float16)v;
  Wfh[g] = h;
  Wfl[g] = (_Float16)((v - (float)h) * 4096.f);
}

// ---------------- chunked aggregation pass ------------------------------
// Pass over src-chunk `chunk`: gathers hit a 3.2MB L2-resident h window.
// fp32 accumulator RMW via nontemporal (keeps window in L2); first pass
// seeds with self-loop, last pass emits fp16 for the streaming GEMM.
__global__ __launch_bounds__(256)
void k_aggc(const _Float16* __restrict__ h, const int* __restrict__ indptr,
            const int2* __restrict__ emeta, const float* __restrict__ dis,
            float* __restrict__ aggf, _Float16* __restrict__ aggh,
            int N, int chunk, int first, int last) {
  int w = (blockIdx.x * 256 + threadIdx.x) >> 6;
  int lane = threadIdx.x & 63;
  if (w >= N) return;
  int g16 = lane >> 4, c8 = lane & 15;
  int base = chunk * N + w;
  int s = indptr[base], e = indptr[base + 1];
  float acc[8];
#pragma unroll
  for (int j = 0; j < 8; ++j) acc[j] = 0.f;

  int i = s;
  for (; i + 16 <= e; i += 16) {
    int2 m[4];
#pragma unroll
    for (int u = 0; u < 4; ++u) m[u] = emeta[i + u * 4 + g16];
    half8v hv[4];
#pragma unroll
    for (int u = 0; u < 4; ++u)
      hv[u] = *(const half8v*)(h + (size_t)m[u].x * C + c8 * 8);
#pragma unroll
    for (int u = 0; u < 4; ++u) {
      float nn = __int_as_float(m[u].y);
#pragma unroll
      for (int j = 0; j < 8; ++j) acc[j] += nn * (float)hv[u][j];
    }
  }
  for (; i + 4 <= e; i += 4) {
    int2 m = emeta[i + g16];
    half8v hv = *(const half8v*)(h + (size_t)m.x * C + c8 * 8);
    float nn = __int_as_float(m.y);
#pragma unroll
    for (int j = 0; j < 8; ++j) acc[j] += nn * (float)hv[j];
  }
  if (i < e) {  // tail 1..3: out-of-range lanes use norm 0
    int idx = i + g16;
    int2 m = make_int2(w, 0);
    if (idx < e) m = emeta[idx];
    half8v hv = *(const half8v*)(h + (size_t)m.x * C + c8 * 8);
    float nn = __int_as_float(m.y);
#pragma unroll
    for (int j = 0; j < 8; ++j) acc[j] += nn * (float)hv[j];
  }
#pragma unroll
  for (int j = 0; j < 8; ++j) {
    acc[j] += __shfl_xor(acc[j], 16, 64);
    acc[j] += __shfl_xor(acc[j], 32, 64);
  }
  if (lane < 16) {
    float* af = aggf + (size_t)w * C + lane * 8;
    float vals[8];
    if (first) {
      float dv = dis[w];
      float dv2 = dv * dv;
      half8v hs = *(const half8v*)(h + (size_t)w * C + lane * 8);
#pragma unroll
      for (int j = 0; j < 8; ++j) vals[j] = dv2 * (float)hs[j];
    } else {
      float4v v0 = __builtin_nontemporal_load((const float4v*)af);
      float4v v1 = __builtin_nontemporal_load((const float4v*)(af + 4));
      vals[0] = v0[0]; vals[1] = v0[1]; vals[2] = v0[2]; vals[3] = v0[3];
      vals[4] = v1[0]; vals[5] = v1[1]; vals[6] = v1[2]; vals[7] = v1[3];
    }
#pragma unroll
    for (int j = 0; j < 8; ++j) vals[j] += acc[j];
    if (last) {
      half8v o;
#pragma unroll
      for (int j = 0; j < 8; ++j) o[j] = (_Float16)vals[j];
      *(half8v*)(aggh + (size_t)w * C + lane * 8) = o;
    } else {
      float4v v0 = {vals[0], vals[1], vals[2], vals[3]};
      float4v v1 = {vals[4], vals[5], vals[6], vals[7]};
      __builtin_nontemporal_store(v0, (float4v*)af);
      __builtin_nontemporal_store(v1, (float4v*)(af + 4));
    }
  }
}

// ---------------- streaming f16 MFMA GEMM (no LDS, no barrier) ----------
__global__ __launch_bounds__(256, 4)
void k_gemm_f16(const _Float16* __restrict__ A,
                const _Float16* __restrict__ Wfh, const _Float16* __restrict__ Wfl,
                const float* __restrict__ bias, const _Float16* __restrict__ skip,
                _Float16* __restrict__ out, int M, int relu) {
  int t = threadIdx.x;
  int r0 = blockIdx.x * 64;
  int w = t >> 6, lane = t & 63;
  int m0 = w * 16, lm = lane & 15, lq = lane >> 4;
  int row = r0 + m0 + lm;
  if (row >= M) row = M - 1;
  const _Float16* Ar = A + (size_t)row * C;

  float4v acch[8], accl[8];
#pragma unroll
  for (int j = 0; j < 8; ++j) {
    acch[j] = (float4v){0.f, 0.f, 0.f, 0.f};
    accl[j] = (float4v){0.f, 0.f, 0.f, 0.f};
  }
#pragma unroll
  for (int kk = 0; kk < 4; ++kk) {
    half8v a = *(const half8v*)(Ar + kk * 32 + lq * 8);
#pragma unroll
    for (int j = 0; j < 8; ++j) {
      int fi = ((kk * 8 + j) * 64 + lane) << 3;
      half8v bh = *(const half8v*)(Wfh + fi);
      half8v bl = *(const half8v*)(Wfl + fi);
      acch[j] = __builtin_amdgcn_mfma_f32_16x16x32_f16(a, bh, acch[j], 0, 0, 0);
      accl[j] = __builtin_amdgcn_mfma_f32_16x16x32_f16(a, bl, accl[j], 0, 0, 0);
    }
  }
#pragma unroll
  for (int j = 0; j < 8; ++j) {
    int n = j * 16 + lm;
    float bv = bias ? bias[n] : 0.f;
#pragma unroll
    for (int r = 0; r < 4; ++r) {
      int m = r0 + m0 + lq * 4 + r;
      if (m >= M) continue;
      float v = acch[j][r] + accl[j][r] * (1.f / 4096.f) + bv;
      if (skip) v += (float)skip[(size_t)m * C + n];
      if (relu) v = fmaxf(v, 0.f);
      out[(size_t)m * C + n] = (_Float16)v;
    }
  }
}

// ---------------- fused edge MLP (fp16, CSR order) -----------------------
__global__ __launch_bounds__(256, 6)
void k_edge(const _Float16* __restrict__ P, const _Float16* __restrict__ Q,
            const int2* __restrict__ epair, const _Float16* __restrict__ Wf,
            const float* __restrict__ b1, const float* __restrict__ w2,
            const float* __restrict__ b2, float* __restrict__ tmpout, int E) {
  __shared__ __align__(16) _Float16 Et[64 * 128];
  int t = threadIdx.x;
  int p0 = blockIdx.x * 64;
  {
    int el = t >> 2, p4 = t & 3;
    int p = p0 + el;
    if (p >= E) p = E - 1;
    int2 rc = epair[p];
    const _Float16* Pp = P + (size_t)rc.x * C + p4 * 32;
    const _Float16* Qp = Q + (size_t)rc.y * C + p4 * 32;
#pragma unroll
    for (int i = 0; i < 4; ++i) {
      half8v a = *(const half8v*)(Pp + 8 * i);
      half8v b = *(const half8v*)(Qp + 8 * i);
      half8v sum = a + b;
      half8v o;
#pragma unroll
      for (int j = 0; j < 8; ++j) {
        _Float16 v = sum[j];
        o[j] = (v > (_Float16)0.f) ? v : (_Float16)0.f;
      }
      *(half8v*)swzh(Et, el, p4 * 4 + i) = o;
    }
  }
  __syncthreads();

  int w = t >> 6, lane = t & 63;
  int m0 = w * 16;
  int lm = lane & 15, lq = lane >> 4;
  float4v acc[8];
#pragma unroll
  for (int j = 0; j < 8; ++j) acc[j] = (float4v){0.f, 0.f, 0.f, 0.f};

#pragma unroll
  for (int kk = 0; kk < 4; ++kk) {
    int ch = kk * 4 + lq;
    half8v ah = *(const half8v*)swzh(Et, m0 + lm, ch);
#pragma unroll
    for (int j = 0; j < 8; ++j) {
      half8v b = *(const half8v*)(Wf + (((kk * 8 + j) * 64 + lane) << 3));
      acc[j] = __builtin_amdgcn_mfma_f32_16x16x32_f16(ah, b, acc[j], 0, 0, 0);
    }
  }

  float partv[4] = {0.f, 0.f, 0.f, 0.f};
#pragma unroll
  for (int j = 0; j < 8; ++j) {
    int n = j * 16 + lm;
    float b1v = b1[n], w2v = w2[n];
#pragma unroll
    for (int r = 0; r < 4; ++r) {
      float e2 = fmaxf(acc[j][r] + b1v, 0.f);
      partv[r] = fmaf(e2, w2v, partv[r]);
    }
  }
#pragma unroll
  for (int off = 1; off < 16; off <<= 1) {
#pragma unroll
    for (int r = 0; r < 4; ++r) partv[r] += __shfl_xor(partv[r], off, 64);
  }
  if (lm == 0) {
    float bb = b2[0];
#pragma unroll
    for (int r = 0; r < 4; ++r) {
      int p = p0 + m0 + lq * 4 + r;
      if (p < E) tmpout[p] = partv[r] + bb;  // coalesced (CSR order)
    }
  }
}

// ---------------- permute: out[e] = tmp[inv[e]] --------------------------
__global__ void k_perm(const float* __restrict__ tmp, const int* __restrict__ inv,
                       float* __restrict__ out, int E) {
  int e = blockIdx.x * 256 + threadIdx.x;
  if (e < E) out[e] = tmp[inv[e]];
}

// ---------------- host ---------------------------------------------------
extern "C" void kernel_launch(void* const* d_in, const int* in_sizes, int n_in,
                              void* d_out, int out_size, void* d_ws, size_t ws_size,
                              hipStream_t stream) {
  const float* x       = (const float*)d_in[0];
  const int*   ei      = (const int*)d_in[1];
  const float* convs_W = (const float*)d_in[2];
  const float* convs_b = (const float*)d_in[3];
  const float* fc0_W   = (const float*)d_in[4];
  const float* fc0_b   = (const float*)d_in[5];
  const float* fc1_W   = (const float*)d_in[6];
  const float* fc1_b   = (const float*)d_in[7];
  const float* fc2_W   = (const float*)d_in[8];
  const float* fc2_b   = (const float*)d_in[9];
  float* out = (float*)d_out;

  const int N = in_sizes[0] / C;        // 50000
  const int E = in_sizes[1] / 2;        // 1600000
  const int L = in_sizes[2] / (C * C);  // 8
  const int* row = ei;
  const int* col = ei + E;
  const int CH = (N + NCH - 1) / NCH;   // 12500 src nodes -> 3.2MB window

  char* wp = (char*)d_ws;
  auto carve = [&](size_t bytes) {
    char* p = wp; wp += (bytes + 255) & ~(size_t)255; return p;
  };
  int*      cntc    = (int*)carve((size_t)NCH * N * 4);
  int*      indptrc = (int*)carve(((size_t)NCH * N + 1) * 4);
  int*      cursorc = (int*)carve((size_t)NCH * N * 4);
  float*    dis     = (float*)carve((size_t)N * 4);
  int2*     emeta   = (int2*)carve((size_t)E * 8);
  int2*     epair   = (int2*)carve((size_t)E * 8);
  int*      inv     = (int*)carve((size_t)E * 4);
  float*    tmpout  = (float*)carve((size_t)E * 4);
  _Float16* Wf      = (_Float16*)carve((size_t)C * C * 2);
  _Float16* Wfh     = (_Float16*)carve((size_t)10 * C * C * 2);
  _Float16* Wfl     = (_Float16*)carve((size_t)10 * C * C * 2);
  _Float16* xh      = (_Float16*)carve((size_t)N * C * 2);
  _Float16* h0      = (_Float16*)carve((size_t)N * C * 2);
  _Float16* h1      = (_Float16*)carve((size_t)N * C * 2);
  float*    aggf    = (float*)carve((size_t)N * C * 4);
  _Float16* aggh    = (_Float16*)carve((size_t)N * C * 2);
  _Float16* Pm      = (_Float16*)carve((size_t)N * C * 2);
  _Float16* Qm      = (_Float16*)carve((size_t)N * C * 2);

  hipMemsetAsync(cntc, 0, (size_t)NCH * N * 4, stream);
  k_degree<<<(E + 255) / 256, 256, 0, stream>>>(row, col, cntc, E, N, CH);
  k_dis<<<(N + 255) / 256, 256, 0, stream>>>(cntc, dis, N);
  k_scan<<<1, 1024, 0, stream>>>(cntc, indptrc, cursorc, NCH * N);
  k_csrfill<<<(E + 255) / 256, 256, 0, stream>>>(row, col, dis, cursorc,
                                                 emeta, epair, inv, E, N, CH);
  k_prepwf<<<C * C / 256, 256, 0, stream>>>(fc1_W, Wf);
  k_prepw2<<<10 * C * C / 256, 256, 0, stream>>>(convs_W, fc0_W, Wfh, Wfl);
  k_cvt<<<(N * C / 4 + 255) / 256, 256, 0, stream>>>(x, xh, N * C / 4);

  int aggBlocks  = (N * 64 + 255) / 256;
  int gemmBlocks = (N + 63) / 64;
  const int MSZ = C * C;

  _Float16* hcur = xh;  // layer-0 input
  _Float16* bufA = h0;  // layer outputs ping-pong
  _Float16* bufB = h1;
  for (int l = 0; l < L; ++l) {
    for (int c = 0; c < NCH; ++c)
      k_aggc<<<aggBlocks, 256, 0, stream>>>(hcur, indptrc, emeta, dis, aggf,
                                            aggh, N, c, c == 0, c == NCH - 1);
    _Float16* hout = (l == 0) ? bufA : ((hcur == bufA) ? bufB : bufA);
    k_gemm_f16<<<gemmBlocks, 256, 0, stream>>>(aggh, Wfh + (size_t)l * MSZ,
                                               Wfl + (size_t)l * MSZ,
                                               convs_b + (size_t)l * C,
                                               (l == 0) ? nullptr : hcur,
                                               hout, N, 1);
    hcur = hout;
  }
  // edge MLP: P = h@fc0_W[:128], Q = h@fc0_W[128:] + b0
  k_gemm_f16<<<gemmBlocks, 256, 0, stream>>>(hcur, Wfh + (size_t)8 * MSZ,
                                             Wfl + (size_t)8 * MSZ, nullptr,
                                             nullptr, Pm, N, 0);
  k_gemm_f16<<<gemmBlocks, 256, 0, stream>>>(hcur, Wfh + (size_t)9 * MSZ,
                                             Wfl + (size_t)9 * MSZ, fc0_b,
                                             nullptr, Qm, N, 0);
  k_edge<<<(E + 63) / 64, 256, 0, stream>>>(Pm, Qm, epair, Wf, fc1_b,
                                            fc2_W, fc2_b, tmpout, E);
  k_perm<<<(E + 255) / 256, 256, 0, stream>>>(tmpout, inv, out, E);
}

// Round 12
// 1061.722 us; speedup vs baseline: 1.8836x; 1.8836x over previous
//
#include <hip/hip_runtime.h>

#define C 128

typedef __attribute__((ext_vector_type(4))) float float4v;
typedef _Float16 half8v __attribute__((ext_vector_type(8)));
typedef _Float16 half4v __attribute__((ext_vector_type(4)));

// LDS swizzle (fp16, row stride 128 elems, 16 chunks of 8)
__device__ __forceinline__ _Float16* swzh(_Float16* base, int row, int chunk) {
  return base + row * 128 + ((chunk ^ (row & 15)) << 3);
}

// ---------------- degree count ------------------------------------------
__global__ void k_degree(const int* __restrict__ col, int* __restrict__ cnt, int E) {
  int e = blockIdx.x * blockDim.x + threadIdx.x;
  if (e < E) atomicAdd(&cnt[col[e]], 1);
}

// ---------------- hierarchical scan (3 kernels, all wide) ---------------
__global__ void k_scan_part(const int* __restrict__ cnt, int* __restrict__ part,
                            int N) {
  __shared__ int sb[256];
  int t = threadIdx.x;
  int i = blockIdx.x * 256 + t;
  sb[t] = (i < N) ? cnt[i] : 0;
  __syncthreads();
#pragma unroll
  for (int off = 128; off > 0; off >>= 1) {
    if (t < off) sb[t] += sb[t + off];
    __syncthreads();
  }
  if (t == 0) part[blockIdx.x] = sb[0];
}

__global__ void k_scan_mid(int* __restrict__ part, int P) {
  __shared__ int sb[256];
  int t = threadIdx.x;
  int v = (t < P) ? part[t] : 0;
  sb[t] = v;
  __syncthreads();
#pragma unroll
  for (int off = 1; off < 256; off <<= 1) {
    int u = (t >= off) ? sb[t - off] : 0;
    __syncthreads();
    sb[t] += u;
    __syncthreads();
  }
  if (t < P) part[t] = sb[t] - v;  // exclusive
}

__global__ void k_scan_fin(const int* __restrict__ cnt, const int* __restrict__ part,
                           float* __restrict__ dis, int* __restrict__ indptr,
                           int* __restrict__ cursor, int N) {
  __shared__ int sb[256];
  int t = threadIdx.x;
  int i = blockIdx.x * 256 + t;
  int v = (i < N) ? cnt[i] : 0;
  sb[t] = v;
  __syncthreads();
#pragma unroll
  for (int off = 1; off < 256; off <<= 1) {
    int u = (t >= off) ? sb[t - off] : 0;
    __syncthreads();
    sb[t] += u;
    __syncthreads();
  }
  int run = part[blockIdx.x] + sb[t] - v;  // exclusive prefix
  if (i < N) {
    indptr[i] = run;
    cursor[i] = run;
    dis[i] = rsqrtf((float)(v + 1));  // +1 self loop
    if (i == N - 1) indptr[N] = run + v;
  }
}

// ---------------- CSR fill (dst-sorted) ---------------------------------
__global__ void k_csrfill(const int* __restrict__ row, const int* __restrict__ col,
                          const float* __restrict__ dis, int* __restrict__ cursor,
                          int2* __restrict__ emeta, int2* __restrict__ epair,
                          int* __restrict__ inv, int E) {
  int e = blockIdx.x * blockDim.x + threadIdx.x;
  if (e >= E) return;
  int r = row[e], c = col[e];
  int pos = atomicAdd(&cursor[c], 1);
  float nrm = dis[r] * dis[c];
  emeta[pos] = make_int2(r, __float_as_int(nrm));
  epair[pos] = make_int2(r, c);
  inv[e] = pos;
}

// ---------------- x fp32 -> fp16 ----------------------------------------
__global__ void k_cvt(const float* __restrict__ x, _Float16* __restrict__ xh, int n4) {
  int i = blockIdx.x * 256 + threadIdx.x;
  if (i >= n4) return;
  float4 v = ((const float4*)x)[i];
  half4v o = {(_Float16)v.x, (_Float16)v.y, (_Float16)v.z, (_Float16)v.w};
  *(half4v*)(xh + i * 4) = o;
}

// ---------------- W1 -> fp16 fragment-major table (fc1) ------------------
__global__ void k_prepwf(const float* __restrict__ W1, _Float16* __restrict__ Wf) {
  int idx = blockIdx.x * 256 + threadIdx.x;  // 16384
  int e = idx & 7, lane = (idx >> 3) & 63, j = (idx >> 9) & 7, kk = idx >> 12;
  int n = j * 16 + (lane & 15);
  int k = (kk * 4 + (lane >> 4)) * 8 + e;
  Wf[idx] = (_Float16)W1[k * C + n];
}

// ------- conv/fc0 W -> fragment-major fp16 hi + scaled-lo (10 mats) ------
// lo = fp16((W - hi) * 4096) keeps residual normal; epilogue recombines
// acc_h + acc_l/4096 -> fp32-equivalent W.
__global__ void k_prepw2(const float* __restrict__ convs_W,
                         const float* __restrict__ fc0_W,
                         _Float16* __restrict__ Wfh, _Float16* __restrict__ Wfl) {
  int g = blockIdx.x * 256 + threadIdx.x;  // [0, 10*16384)
  int mat = g >> 14, idx = g & 16383;
  int e = idx & 7, lane = (idx >> 3) & 63, j = (idx >> 9) & 7, kk = idx >> 12;
  int n = j * 16 + (lane & 15);
  int k = (kk * 4 + (lane >> 4)) * 8 + e;
  const float* src = (mat < 8) ? convs_W + ((size_t)mat << 14)
                               : fc0_W + ((size_t)(mat - 8) << 14);
  float v = src[k * C + n];
  _Float16 h = (_Float16)v;
  Wfh[g] = h;
  Wfl[g] = (_Float16)((v - (float)h) * 4096.f);
}

// ---------------- aggregation (fp16 h -> fp16 agg) -----------------------
// Wave per node; lane = (edge-slot lane>>4, channel-octet lane&15); each
// lane: one 16B half8 load -> 1024B = 4 h-rows per instruction. fp32 accum.
__global__ __launch_bounds__(256)
void k_agg(const _Float16* __restrict__ h, const int* __restrict__ indptr,
           const int2* __restrict__ emeta, const float* __restrict__ dis,
           _Float16* __restrict__ agg, int N) {
  int w = (blockIdx.x * 256 + threadIdx.x) >> 6;
  int lane = threadIdx.x & 63;
  if (w >= N) return;
  int g16 = lane >> 4, c8 = lane & 15;
  int s = indptr[w], e = indptr[w + 1];
  float acc[8];
#pragma unroll
  for (int j = 0; j < 8; ++j) acc[j] = 0.f;

  int i = s;
  for (; i + 16 <= e; i += 16) {  // 4 kB-gathers in flight
    int2 m[4];
#pragma unroll
    for (int u = 0; u < 4; ++u) m[u] = emeta[i + u * 4 + g16];
    half8v hv[4];
#pragma unroll
    for (int u = 0; u < 4; ++u)
      hv[u] = *(const half8v*)(h + (size_t)m[u].x * C + c8 * 8);
#pragma unroll
    for (int u = 0; u < 4; ++u) {
      float nn = __int_as_float(m[u].y);
#pragma unroll
      for (int j = 0; j < 8; ++j) acc[j] += nn * (float)hv[u][j];
    }
  }
  for (; i + 4 <= e; i += 4) {
    int2 m = emeta[i + g16];
    half8v hv = *(const half8v*)(h + (size_t)m.x * C + c8 * 8);
    float nn = __int_as_float(m.y);
#pragma unroll
    for (int j = 0; j < 8; ++j) acc[j] += nn * (float)hv[j];
  }
  if (i < e) {  // tail 1..3: out-of-range lanes use norm 0
    int idx = i + g16;
    int2 m = make_int2(w, 0);
    if (idx < e) m = emeta[idx];
    half8v hv = *(const half8v*)(h + (size_t)m.x * C + c8 * 8);
    float nn = __int_as_float(m.y);
#pragma unroll
    for (int j = 0; j < 8; ++j) acc[j] += nn * (float)hv[j];
  }
#pragma unroll
  for (int j = 0; j < 8; ++j) {
    acc[j] += __shfl_xor(acc[j], 16, 64);
    acc[j] += __shfl_xor(acc[j], 32, 64);
  }
  if (lane < 16) {
    float dv = dis[w];
    float dv2 = dv * dv;
    half8v hs = *(const half8v*)(h + (size_t)w * C + lane * 8);
    half8v o;
#pragma unroll
    for (int j = 0; j < 8; ++j) o[j] = (_Float16)(acc[j] + dv2 * (float)hs[j]);
    *(half8v*)(agg + (size_t)w * C + lane * 8) = o;
  }
}

// ---------------- streaming f16 MFMA GEMM (no LDS, no barrier) ----------
__global__ __launch_bounds__(256, 4)
void k_gemm_f16(const _Float16* __restrict__ A,
                const _Float16* __restrict__ Wfh, const _Float16* __restrict__ Wfl,
                const float* __restrict__ bias, const _Float16* __restrict__ skip,
                _Float16* __restrict__ out, int M, int relu) {
  int t = threadIdx.x;
  int r0 = blockIdx.x * 64;
  int w = t >> 6, lane = t & 63;
  int m0 = w * 16, lm = lane & 15, lq = lane >> 4;
  int row = r0 + m0 + lm;
  if (row >= M) row = M - 1;
  const _Float16* Ar = A + (size_t)row * C;

  float4v acch[8], accl[8];
#pragma unroll
  for (int j = 0; j < 8; ++j) {
    acch[j] = (float4v){0.f, 0.f, 0.f, 0.f};
    accl[j] = (float4v){0.f, 0.f, 0.f, 0.f};
  }
#pragma unroll
  for (int kk = 0; kk < 4; ++kk) {
    half8v a = *(const half8v*)(Ar + kk * 32 + lq * 8);
#pragma unroll
    for (int j = 0; j < 8; ++j) {
      int fi = ((kk * 8 + j) * 64 + lane) << 3;
      half8v bh = *(const half8v*)(Wfh + fi);
      half8v bl = *(const half8v*)(Wfl + fi);
      acch[j] = __builtin_amdgcn_mfma_f32_16x16x32_f16(a, bh, acch[j], 0, 0, 0);
      accl[j] = __builtin_amdgcn_mfma_f32_16x16x32_f16(a, bl, accl[j], 0, 0, 0);
    }
  }
#pragma unroll
  for (int j = 0; j < 8; ++j) {
    int n = j * 16 + lm;
    float bv = bias ? bias[n] : 0.f;
#pragma unroll
    for (int r = 0; r < 4; ++r) {
      int m = r0 + m0 + lq * 4 + r;
      if (m >= M) continue;
      float v = acch[j][r] + accl[j][r] * (1.f / 4096.f) + bv;
      if (skip) v += (float)skip[(size_t)m * C + n];
      if (relu) v = fmaxf(v, 0.f);
      out[(size_t)m * C + n] = (_Float16)v;
    }
  }
}

// ---------------- fused edge MLP (fp16, CSR order) -----------------------
__global__ __launch_bounds__(256, 6)
void k_edge(const _Float16* __restrict__ P, const _Float16* __restrict__ Q,
            const int2* __restrict__ epair, const _Float16* __restrict__ Wf,
            const float* __restrict__ b1, const float* __restrict__ w2,
            const float* __restrict__ b2, float* __restrict__ tmpout, int E) {
  __shared__ __align__(16) _Float16 Et[64 * 128];
  int t = threadIdx.x;
  int p0 = blockIdx.x * 64;
  {
    int el = t >> 2, p4 = t & 3;
    int p = p0 + el;
    if (p >= E) p = E - 1;
    int2 rc = epair[p];
    const _Float16* Pp = P + (size_t)rc.x * C + p4 * 32;
    const _Float16* Qp = Q + (size_t)rc.y * C + p4 * 32;
#pragma unroll
    for (int i = 0; i < 4; ++i) {
      half8v a = *(const half8v*)(Pp + 8 * i);
      half8v b = *(const half8v*)(Qp + 8 * i);
      half8v sum = a + b;
      half8v o;
#pragma unroll
      for (int j = 0; j < 8; ++j) {
        _Float16 v = sum[j];
        o[j] = (v > (_Float16)0.f) ? v : (_Float16)0.f;
      }
      *(half8v*)swzh(Et, el, p4 * 4 + i) = o;
    }
  }
  __syncthreads();

  int w = t >> 6, lane = t & 63;
  int m0 = w * 16;
  int lm = lane & 15, lq = lane >> 4;
  float4v acc[8];
#pragma unroll
  for (int j = 0; j < 8; ++j) acc[j] = (float4v){0.f, 0.f, 0.f, 0.f};

#pragma unroll
  for (int kk = 0; kk < 4; ++kk) {
    int ch = kk * 4 + lq;
    half8v ah = *(const half8v*)swzh(Et, m0 + lm, ch);
#pragma unroll
    for (int j = 0; j < 8; ++j) {
      half8v b = *(const half8v*)(Wf + (((kk * 8 + j) * 64 + lane) << 3));
      acc[j] = __builtin_amdgcn_mfma_f32_16x16x32_f16(ah, b, acc[j], 0, 0, 0);
    }
  }

  float partv[4] = {0.f, 0.f, 0.f, 0.f};
#pragma unroll
  for (int j = 0; j < 8; ++j) {
    int n = j * 16 + lm;
    float b1v = b1[n], w2v = w2[n];
#pragma unroll
    for (int r = 0; r < 4; ++r) {
      float e2 = fmaxf(acc[j][r] + b1v, 0.f);
      partv[r] = fmaf(e2, w2v, partv[r]);
    }
  }
#pragma unroll
  for (int off = 1; off < 16; off <<= 1) {
#pragma unroll
    for (int r = 0; r < 4; ++r) partv[r] += __shfl_xor(partv[r], off, 64);
  }
  if (lm == 0) {
    float bb = b2[0];
#pragma unroll
    for (int r = 0; r < 4; ++r) {
      int p = p0 + m0 + lq * 4 + r;
      if (p < E) tmpout[p] = partv[r] + bb;  // coalesced (CSR order)
    }
  }
}

// ---------------- permute: out[e] = tmp[inv[e]] --------------------------
__global__ void k_perm(const float* __restrict__ tmp, const int* __restrict__ inv,
                       float* __restrict__ out, int E) {
  int e = blockIdx.x * 256 + threadIdx.x;
  if (e < E) out[e] = tmp[inv[e]];
}

// ---------------- host ---------------------------------------------------
extern "C" void kernel_launch(void* const* d_in, const int* in_sizes, int n_in,
                              void* d_out, int out_size, void* d_ws, size_t ws_size,
                              hipStream_t stream) {
  const float* x       = (const float*)d_in[0];
  const int*   ei      = (const int*)d_in[1];
  const float* convs_W = (const float*)d_in[2];
  const float* convs_b = (const float*)d_in[3];
  const float* fc0_W   = (const float*)d_in[4];
  const float* fc0_b   = (const float*)d_in[5];
  const float* fc1_W   = (const float*)d_in[6];
  const float* fc1_b   = (const float*)d_in[7];
  const float* fc2_W   = (const float*)d_in[8];
  const float* fc2_b   = (const float*)d_in[9];
  float* out = (float*)d_out;

  const int N = in_sizes[0] / C;        // 50000
  const int E = in_sizes[1] / 2;        // 1600000
  const int L = in_sizes[2] / (C * C);  // 8
  const int* row = ei;
  const int* col = ei + E;
  const int SB = (N + 255) / 256;       // 196 scan blocks (<=256)

  char* wp = (char*)d_ws;
  auto carve = [&](size_t bytes) {
    char* p = wp; wp += (bytes + 255) & ~(size_t)255; return p;
  };
  int*      cnt    = (int*)carve((size_t)N * 4);
  int*      part   = (int*)carve((size_t)SB * 4);
  int*      indptr = (int*)carve((size_t)(N + 1) * 4);
  int*      cursor = (int*)carve((size_t)N * 4);
  float*    dis    = (float*)carve((size_t)N * 4);
  int2*     emeta  = (int2*)carve((size_t)E * 8);
  int2*     epair  = (int2*)carve((size_t)E * 8);
  int*      inv    = (int*)carve((size_t)E * 4);
  float*    tmpout = (float*)carve((size_t)E * 4);
  _Float16* Wf     = (_Float16*)carve((size_t)C * C * 2);
  _Float16* Wfh    = (_Float16*)carve((size_t)10 * C * C * 2);
  _Float16* Wfl    = (_Float16*)carve((size_t)10 * C * C * 2);
  _Float16* xh     = (_Float16*)carve((size_t)N * C * 2);
  _Float16* h0     = (_Float16*)carve((size_t)N * C * 2);
  _Float16* h1     = (_Float16*)carve((size_t)N * C * 2);
  _Float16* aggb   = (_Float16*)carve((size_t)N * C * 2);
  _Float16* Pm     = (_Float16*)carve((size_t)N * C * 2);
  _Float16* Qm     = (_Float16*)carve((size_t)N * C * 2);

  hipMemsetAsync(cnt, 0, (size_t)N * 4, stream);
  k_degree<<<(E + 255) / 256, 256, 0, stream>>>(col, cnt, E);
  k_scan_part<<<SB, 256, 0, stream>>>(cnt, part, N);
  k_scan_mid<<<1, 256, 0, stream>>>(part, SB);
  k_scan_fin<<<SB, 256, 0, stream>>>(cnt, part, dis, indptr, cursor, N);
  k_csrfill<<<(E + 255) / 256, 256, 0, stream>>>(row, col, dis, cursor,
                                                 emeta, epair, inv, E);
  k_prepwf<<<C * C / 256, 256, 0, stream>>>(fc1_W, Wf);
  k_prepw2<<<10 * C * C / 256, 256, 0, stream>>>(convs_W, fc0_W, Wfh, Wfl);
  k_cvt<<<(N * C / 4 + 255) / 256, 256, 0, stream>>>(x, xh, N * C / 4);

  int aggBlocks  = (N * 64 + 255) / 256;
  int gemmBlocks = (N + 63) / 64;
  const int MSZ = C * C;

  // layer 0 (no skip)
  k_agg<<<aggBlocks, 256, 0, stream>>>(xh, indptr, emeta, dis, aggb, N);
  k_gemm_f16<<<gemmBlocks, 256, 0, stream>>>(aggb, Wfh, Wfl, convs_b,
                                             nullptr, h0, N, 1);
  _Float16* hcur = h0; _Float16* hoth = h1;
  for (int l = 1; l < L; ++l) {
    k_agg<<<aggBlocks, 256, 0, stream>>>(hcur, indptr, emeta, dis, aggb, N);
    k_gemm_f16<<<gemmBlocks, 256, 0, stream>>>(aggb, Wfh + (size_t)l * MSZ,
                                               Wfl + (size_t)l * MSZ,
                                               convs_b + (size_t)l * C, hcur,
                                               hoth, N, 1);
    _Float16* tmp = hcur; hcur = hoth; hoth = tmp;
  }
  // edge MLP: P = h@fc0_W[:128], Q = h@fc0_W[128:] + b0
  k_gemm_f16<<<gemmBlocks, 256, 0, stream>>>(hcur, Wfh + (size_t)8 * MSZ,
                                             Wfl + (size_t)8 * MSZ, nullptr,
                                             nullptr, Pm, N, 0);
  k_gemm_f16<<<gemmBlocks, 256, 0, stream>>>(hcur, Wfh + (size_t)9 * MSZ,
                                             Wfl + (size_t)9 * MSZ, fc0_b,
                                             nullptr, Qm, N, 0);
  k_edge<<<(E + 63) / 64, 256, 0, stream>>>(Pm, Qm, epair, Wf, fc1_b,
                                            fc2_W, fc2_b, tmpout, E);
  k_perm<<<(E + 255) / 256, 256, 0, stream>>>(tmpout, inv, out, E);
}